// Round 2
// baseline (95.568 us; speedup 1.0000x reference)
//
#include <hip/hip_runtime.h>
#include <hip/hip_bf16.h>

// ============================================================================
// AdaptiveDiffusionConv: out[b,n,o,t] = relu( sum_{k,f} Theta[k,f,o] * rhs_k )
//   rhs0 = x, rhs1 = a^T x, rhs2 = a^T rhs1   (a = adj .* spatial_attention)
// (a@a)^T x = a^T (a^T x)  -> two [1024x1024]^T @ [1024x192] batched GEMMs.
//
// R2: GEMM with global_load_lds (swizzled source, linear LDS), A-operand
// direct-from-global (L2-hot), 2-phase pipeline, 512 blocks (2/CU).
// final_contract: LDS output staging for coalesced float4 stores.
// ============================================================================

typedef __attribute__((ext_vector_type(8))) __bf16 bf16x8;
typedef __attribute__((ext_vector_type(4))) float  f32x4;
typedef __attribute__((ext_vector_type(8))) short  short8;

__device__ inline unsigned short f32_to_bf16(float f) {
    unsigned int u = __builtin_bit_cast(unsigned int, f);
    unsigned int r = u + 0x7FFFu + ((u >> 16) & 1u);   // RNE
    return (unsigned short)(r >> 16);
}
__device__ inline float bf16_to_f32(unsigned short u) {
    unsigned int x = ((unsigned int)u) << 16;
    return __builtin_bit_cast(float, x);
}

__device__ inline void gload_lds16(const void* gsrc, void* ldst) {
    __builtin_amdgcn_global_load_lds(
        (const __attribute__((address_space(1))) unsigned int*)gsrc,
        (__attribute__((address_space(3))) unsigned int*)ldst,
        16, 0, 0);
}

// ---------------------------------------------------------------------------
// prep_a: aT[b][n][m] = bf16(adj[m][n] * sa[b][m][n]); 32x32 LDS tile transpose
// ---------------------------------------------------------------------------
__global__ void prep_a(const float* __restrict__ sa, const float* __restrict__ adj,
                       unsigned short* __restrict__ aT)
{
    __shared__ float tile[32][33];
    const int b  = blockIdx.z;
    const int m0 = blockIdx.y * 32;
    const int n0 = blockIdx.x * 32;
    const int tid = threadIdx.x;
    const int c  = tid & 31;
    const int r4 = tid >> 5;          // 0..7
    const float* sab = sa + (size_t)b * 1024 * 1024;
#pragma unroll
    for (int i = 0; i < 4; i++) {
        int rr = r4 + i * 8;
        size_t idx = (size_t)(m0 + rr) * 1024 + (n0 + c);
        tile[rr][c] = adj[idx] * sab[idx];
    }
    __syncthreads();
    unsigned short* aTb = aT + (size_t)b * 1024 * 1024;
#pragma unroll
    for (int i = 0; i < 4; i++) {
        int rr = r4 + i * 8;          // n offset in output
        aTb[(size_t)(n0 + rr) * 1024 + (m0 + c)] = f32_to_bf16(tile[c][rr]);
    }
}

// ---------------------------------------------------------------------------
// prep_x: xT[b][j][m] = bf16(x[b][m][j]), j = f*12+t (192)
// ---------------------------------------------------------------------------
__global__ void prep_x(const float* __restrict__ x, unsigned short* __restrict__ xT)
{
    __shared__ float tile[32][33];
    const int b  = blockIdx.z;
    const int j0 = blockIdx.y * 32;
    const int m0 = blockIdx.x * 32;
    const int tid = threadIdx.x;
    const int c  = tid & 31;
    const int r4 = tid >> 5;
    const float* xb = x + (size_t)b * 1024 * 192;
#pragma unroll
    for (int i = 0; i < 4; i++) {
        int rr = r4 + i * 8;          // m
        tile[rr][c] = xb[(size_t)(m0 + rr) * 192 + (j0 + c)];
    }
    __syncthreads();
    unsigned short* xTb = xT + (size_t)b * 192 * 1024;
#pragma unroll
    for (int i = 0; i < 4; i++) {
        int rr = r4 + i * 8;          // j
        xTb[(size_t)(j0 + rr) * 1024 + (m0 + c)] = f32_to_bf16(tile[c][rr]);
    }
}

// ---------------------------------------------------------------------------
// gemm_tn: Cout[b][j][n] (bf16) = sum_m Aop[b][j][m] * Bop[b][n][m]
//   Aop: [B][192][1024] row-major (k=m contiguous) -> direct-from-global frags
//   Bop: [B][1024][1024] (aT)  -> global_load_lds, XOR-swizzled source
// block tile 96j x 64n, BK=64, 4 waves (2x2), wave tile 48x32.
// grid (16 n, 2 j, 16 b) = 512 blocks -> 2 blocks/CU.
// LDS: Blds[2][64 rows][64 el], linear, 128B rows; swizzle c16' = c16^(row&7).
// ---------------------------------------------------------------------------
__global__ __launch_bounds__(256, 2)
void gemm_tn(const unsigned short* __restrict__ Aop,
             const unsigned short* __restrict__ Bop,
             unsigned short* __restrict__ Cout)
{
    const int b  = blockIdx.z;
    const int j0 = blockIdx.y * 96;
    const int n0 = blockIdx.x * 64;
    const unsigned short* Ab = Aop + (size_t)b * 192 * 1024;
    const unsigned short* Bb = Bop + (size_t)b * 1024 * 1024;

    __shared__ unsigned short Blds[2][64 * 64];   // 2 x 8KB, linear (no pad!)

    const int tid  = threadIdx.x;
    const int lane = tid & 63;
    const int wave = tid >> 6;      // 0..3
    const int wj   = wave >> 1;     // 0..1
    const int wn   = wave & 1;      // 0..1
    const int lr   = lane & 15;
    const int lk8  = (lane >> 4) * 8;

    // staging: chunk c covers rows 8c..8c+7 (1024B); lane l -> row 8c+(l>>3),
    // 16B-group (l&7); source group pre-swizzled: g16 = (l&7) ^ (l>>3)
    const int srow = lane >> 3;            // 0..7
    const int sg16 = (lane & 7) ^ srow;    // swizzled source 16B-group
    const int sc0  = wave * 2;             // this wave's chunks: sc0, sc0+1

    f32x4 acc[3][2];
#pragma unroll
    for (int i = 0; i < 3; i++)
#pragma unroll
        for (int j = 0; j < 2; j++) acc[i][j] = f32x4{0.f, 0.f, 0.f, 0.f};

    // A fragment row pointers (rows fixed per lane; col = m0 + h*32 + lk8)
    const unsigned short* Arow[3];
#pragma unroll
    for (int ri = 0; ri < 3; ri++)
        Arow[ri] = Ab + (size_t)(j0 + wj * 48 + ri * 16 + lr) * 1024 + lk8;

    bf16x8 Ac[2][3], An[2][3];

    // ---- prologue: stage B(m0=0) into buf0, load A(m0=0)
#pragma unroll
    for (int i = 0; i < 2; i++) {
        int c = sc0 + i;
        gload_lds16(Bb + (size_t)(n0 + 8 * c + srow) * 1024 + sg16 * 8,
                    &Blds[0][c * 512]);
    }
#pragma unroll
    for (int h = 0; h < 2; h++)
#pragma unroll
        for (int ri = 0; ri < 3; ri++)
            Ac[h][ri] = __builtin_bit_cast(bf16x8,
                *reinterpret_cast<const short8*>(Arow[ri] + h * 32));
    __syncthreads();

    int cur = 0;
    for (int t = 0; t < 16; ++t) {
        const int m0 = t * 64;
        if (t < 15) {
            // issue next-tile B stage + A prefetch FIRST (T3 recipe)
#pragma unroll
            for (int i = 0; i < 2; i++) {
                int c = sc0 + i;
                gload_lds16(Bb + (size_t)(n0 + 8 * c + srow) * 1024 + (m0 + 64) + sg16 * 8,
                            &Blds[cur ^ 1][c * 512]);
            }
#pragma unroll
            for (int h = 0; h < 2; h++)
#pragma unroll
                for (int ri = 0; ri < 3; ri++)
                    An[h][ri] = __builtin_bit_cast(bf16x8,
                        *reinterpret_cast<const short8*>(Arow[ri] + m0 + 64 + h * 32));
        }
        // ---- B fragments from swizzled LDS
        bf16x8 Bfr[2][2];
        const char* base = (const char*)&Blds[cur][0];
#pragma unroll
        for (int h = 0; h < 2; h++)
#pragma unroll
            for (int ci = 0; ci < 2; ci++) {
                int row = wn * 32 + ci * 16 + lr;
                int c16 = (h * 32 + lk8) >> 3;          // 0,1,4,5
                int sw  = c16 ^ (row & 7);
                Bfr[h][ci] = __builtin_bit_cast(bf16x8,
                    *reinterpret_cast<const short8*>(base + row * 128 + sw * 16));
            }
#pragma unroll
        for (int h = 0; h < 2; h++)
#pragma unroll
            for (int ri = 0; ri < 3; ri++)
#pragma unroll
                for (int ci = 0; ci < 2; ci++)
                    acc[ri][ci] = __builtin_amdgcn_mfma_f32_16x16x32_bf16(
                        Ac[h][ri], Bfr[h][ci], acc[ri][ci], 0, 0, 0);
        __syncthreads();   // drains stage (vmcnt) + protects buf reuse
        if (t < 15) {
#pragma unroll
            for (int h = 0; h < 2; h++)
#pragma unroll
                for (int ri = 0; ri < 3; ri++) Ac[h][ri] = An[h][ri];
            cur ^= 1;
        }
    }

    // ---- epilogue: D layout col = lane&15, row = (lane>>4)*4 + reg
    unsigned short* Cb = Cout + (size_t)b * 192 * 1024;
    const int jw = j0 + wj * 48;
    const int nw = n0 + wn * 32;
#pragma unroll
    for (int ri = 0; ri < 3; ri++)
#pragma unroll
        for (int ci = 0; ci < 2; ci++) {
            int col = nw + ci * 16 + lr;
#pragma unroll
            for (int r = 0; r < 4; r++) {
                int row = jw + ri * 16 + (lane >> 4) * 4 + r;
                Cb[(size_t)row * 1024 + col] = f32_to_bf16(acc[ri][ci][r]);
            }
        }
}

// ---------------------------------------------------------------------------
// final_contract: out[b,n,o,t] = relu( sum_f Th0[f,o]*xT + Th1[f,o]*r1 + Th2[f,o]*r2 )
// block = (b, 64-n chunk); threads (64 n_local x 4 tq, tq==3 idle in compute).
// Output tile staged in LDS -> one coalesced float4 copy of 48KB contiguous.
// grid (16 n-chunks, 16 b) x 256
// ---------------------------------------------------------------------------
__global__ __launch_bounds__(256)
void final_contract(const unsigned short* __restrict__ xT,
                    const unsigned short* __restrict__ r1,
                    const unsigned short* __restrict__ r2,
                    const float* __restrict__ Theta,   // [3][16][16]
                    float* __restrict__ out)           // [B][1024][16][12]
{
    __shared__ float th[768];
    __shared__ float obuf[64 * 192];   // 48KB out tile

    const int tid = threadIdx.x;
    for (int i = tid; i < 768; i += 256) th[i] = Theta[i];
    __syncthreads();

    const int b  = blockIdx.y;
    const int n0 = blockIdx.x * 64;
    const int nl = tid & 63;          // consecutive lanes = consecutive n (coalesced)
    const int tq = tid >> 6;          // 0..3 (3 idle)

    if (tq < 3) {
        float acc[4][16];
#pragma unroll
        for (int tt = 0; tt < 4; tt++)
#pragma unroll
            for (int o = 0; o < 16; o++) acc[tt][o] = 0.f;

        const size_t basep = (size_t)b * 192 * 1024 + n0 + nl;
#pragma unroll
        for (int f = 0; f < 16; f++) {
            size_t off = basep + (size_t)(f * 12 + tq * 4) * 1024;
            float v0[4], v1[4], v2[4];
#pragma unroll
            for (int tt = 0; tt < 4; tt++) {
                v0[tt] = bf16_to_f32(xT[off + (size_t)tt * 1024]);
                v1[tt] = bf16_to_f32(r1[off + (size_t)tt * 1024]);
                v2[tt] = bf16_to_f32(r2[off + (size_t)tt * 1024]);
            }
            const f32x4* t0 = reinterpret_cast<const f32x4*>(&th[0 * 256 + f * 16]);
            const f32x4* t1 = reinterpret_cast<const f32x4*>(&th[1 * 256 + f * 16]);
            const f32x4* t2 = reinterpret_cast<const f32x4*>(&th[2 * 256 + f * 16]);
#pragma unroll
            for (int q = 0; q < 4; q++) {
                f32x4 w0 = t0[q], w1 = t1[q], w2 = t2[q];
#pragma unroll
                for (int tt = 0; tt < 4; tt++)
#pragma unroll
                    for (int e = 0; e < 4; e++)
                        acc[tt][q * 4 + e] += v0[tt] * w0[e] + v1[tt] * w1[e] + v2[tt] * w2[e];
            }
        }
#pragma unroll
        for (int o = 0; o < 16; o++)
#pragma unroll
            for (int tt = 0; tt < 4; tt++)
                obuf[nl * 192 + o * 12 + tq * 4 + tt] = fmaxf(acc[tt][o], 0.f);
    }
    __syncthreads();

    // coalesced copy: 64x192 f32 = 3072 float4, 12 per thread
    float* outp = out + ((size_t)b * 1024 + n0) * 192;
    const f32x4* src = reinterpret_cast<const f32x4*>(obuf);
    f32x4* dst = reinterpret_cast<f32x4*>(outp);
#pragma unroll
    for (int i = 0; i < 12; i++)
        dst[tid + i * 256] = src[tid + i * 256];
}

// ---------------------------------------------------------------------------
extern "C" void kernel_launch(void* const* d_in, const int* in_sizes, int n_in,
                              void* d_out, int out_size, void* d_ws, size_t ws_size,
                              hipStream_t stream)
{
    const float* x     = (const float*)d_in[0];   // [16][1024][16][12]
    const float* sa    = (const float*)d_in[1];   // [16][1024][1024]
    const float* adj   = (const float*)d_in[2];   // [1024][1024]
    const float* Theta = (const float*)d_in[3];   // [3][16][16]
    float* out = (float*)d_out;

    char* ws = (char*)d_ws;
    const size_t SZ_AT = (size_t)16 * 1024 * 1024 * 2;  // 32 MB
    const size_t SZ_XT = (size_t)16 * 192  * 1024 * 2;  //  6 MB
    unsigned short* aT = (unsigned short*)ws;
    unsigned short* xT = (unsigned short*)(ws + SZ_AT);
    unsigned short* r1 = (unsigned short*)(ws + SZ_AT + SZ_XT);
    unsigned short* r2 = (unsigned short*)(ws + SZ_AT + 2 * SZ_XT);

    prep_a<<<dim3(32, 32, 16), 256, 0, stream>>>(sa, adj, aT);
    prep_x<<<dim3(32, 6, 16), 256, 0, stream>>>(x, xT);
    gemm_tn<<<dim3(16, 2, 16), 256, 0, stream>>>(xT, aT, r1);   // rhs1T
    gemm_tn<<<dim3(16, 2, 16), 256, 0, stream>>>(r1, aT, r2);   // rhs2T
    final_contract<<<dim3(16, 16), 256, 0, stream>>>(xT, r1, r2, Theta, out);
}

// Round 3
// 76.622 us; speedup vs baseline: 1.2473x; 1.2473x over previous
//
#include <hip/hip_runtime.h>
#include <hip/hip_bf16.h>

// ============================================================================
// AdaptiveDiffusionConv: out[b,n,o,t] = relu( sum_{k,f} Theta[k,f,o] * rhs_k )
//   rhs0 = x, rhs1 = a^T x, rhs2 = a^T rhs1   (a = adj .* spatial_attention)
// (a@a)^T x = a^T (a^T x)  -> two [1024x1024]^T @ [1024x192] batched GEMMs.
//
// R3: GEMM = 96x128 tile, BK=64, 3-deep global_load_lds pipeline with raw
// s_barrier + counted vmcnt(10) (never drained to 0), XOR-swizzled B staging,
// A direct global->reg prefetched 1 step ahead, full K-loop unroll.
// ============================================================================

typedef __attribute__((ext_vector_type(8))) __bf16 bf16x8;
typedef __attribute__((ext_vector_type(4))) float  f32x4;
typedef __attribute__((ext_vector_type(8))) short  short8;

__device__ inline unsigned short f32_to_bf16(float f) {
    unsigned int u = __builtin_bit_cast(unsigned int, f);
    unsigned int r = u + 0x7FFFu + ((u >> 16) & 1u);   // RNE
    return (unsigned short)(r >> 16);
}
__device__ inline float bf16_to_f32(unsigned short u) {
    unsigned int x = ((unsigned int)u) << 16;
    return __builtin_bit_cast(float, x);
}

__device__ inline void gload_lds16(const void* gsrc, void* ldst) {
    __builtin_amdgcn_global_load_lds(
        (const __attribute__((address_space(1))) unsigned int*)gsrc,
        (__attribute__((address_space(3))) unsigned int*)ldst,
        16, 0, 0);
}

// ---------------------------------------------------------------------------
// prep_a: aT[b][n][m] = bf16(adj[m][n] * sa[b][m][n]); 32x32 LDS tile transpose
// ---------------------------------------------------------------------------
__global__ void prep_a(const float* __restrict__ sa, const float* __restrict__ adj,
                       unsigned short* __restrict__ aT)
{
    __shared__ float tile[32][33];
    const int b  = blockIdx.z;
    const int m0 = blockIdx.y * 32;
    const int n0 = blockIdx.x * 32;
    const int tid = threadIdx.x;
    const int c  = tid & 31;
    const int r4 = tid >> 5;          // 0..7
    const float* sab = sa + (size_t)b * 1024 * 1024;
#pragma unroll
    for (int i = 0; i < 4; i++) {
        int rr = r4 + i * 8;
        size_t idx = (size_t)(m0 + rr) * 1024 + (n0 + c);
        tile[rr][c] = adj[idx] * sab[idx];
    }
    __syncthreads();
    unsigned short* aTb = aT + (size_t)b * 1024 * 1024;
#pragma unroll
    for (int i = 0; i < 4; i++) {
        int rr = r4 + i * 8;          // n offset in output
        aTb[(size_t)(n0 + rr) * 1024 + (m0 + c)] = f32_to_bf16(tile[c][rr]);
    }
}

// ---------------------------------------------------------------------------
// prep_x: xT[b][j][m] = bf16(x[b][m][j]), j = f*12+t (192)
// ---------------------------------------------------------------------------
__global__ void prep_x(const float* __restrict__ x, unsigned short* __restrict__ xT)
{
    __shared__ float tile[32][33];
    const int b  = blockIdx.z;
    const int j0 = blockIdx.y * 32;
    const int m0 = blockIdx.x * 32;
    const int tid = threadIdx.x;
    const int c  = tid & 31;
    const int r4 = tid >> 5;
    const float* xb = x + (size_t)b * 1024 * 192;
#pragma unroll
    for (int i = 0; i < 4; i++) {
        int rr = r4 + i * 8;          // m
        tile[rr][c] = xb[(size_t)(m0 + rr) * 192 + (j0 + c)];
    }
    __syncthreads();
    unsigned short* xTb = xT + (size_t)b * 192 * 1024;
#pragma unroll
    for (int i = 0; i < 4; i++) {
        int rr = r4 + i * 8;          // j
        xTb[(size_t)(j0 + rr) * 1024 + (m0 + c)] = f32_to_bf16(tile[c][rr]);
    }
}

// ---------------------------------------------------------------------------
// gemm_tn: Cout[b][j][n] (bf16) = sum_m Aop[b][j][m] * Bop[b][n][m]
//   Aop: [B][192][1024] row-major -> direct-from-global reg frags (L2-hot)
//   Bop: [B][1024][1024] (aT)     -> global_load_lds, XOR-swizzled source
// tile 96j x 128n, BK=64, 4 waves (2x2), wave tile 48x64 (24 MFMA/K-step).
// 3 LDS buffers, raw s_barrier + counted vmcnt(10): stage issued 2 steps
// ahead, A prefetched 1 step ahead; loads NEVER drained to zero in the loop.
// grid (8 n, 2 j, 16 b) = 256 blocks -> 1 block/CU.
// ---------------------------------------------------------------------------
__global__ __launch_bounds__(256, 1)
void gemm_tn(const unsigned short* __restrict__ Aop,
             const unsigned short* __restrict__ Bop,
             unsigned short* __restrict__ Cout)
{
    const int b  = blockIdx.z;
    const int j0 = blockIdx.y * 96;
    const int n0 = blockIdx.x * 128;
    const unsigned short* Ab = Aop + (size_t)b * 192 * 1024;
    const unsigned short* Bb = Bop + (size_t)b * 1024 * 1024;

    __shared__ unsigned short Blds[3][128 * 64];   // 3 x 16KB, linear

    const int tid  = threadIdx.x;
    const int lane = tid & 63;
    const int wave = tid >> 6;      // 0..3
    const int wj   = wave >> 1;     // 0..1
    const int wn   = wave & 1;      // 0..1
    const int lr   = lane & 15;
    const int lg   = lane >> 4;     // 0..3 (k-group)

    // staging: chunk c covers rows 8c..8c+7 (1KB); lane l -> row 8c+(l>>3),
    // dest 16B-group (l&7); source group pre-swizzled: (l&7)^(l>>3)
    const int srow = lane >> 3;            // 0..7
    const int sg16 = (lane & 7) ^ srow;    // swizzled source 16B-group

    f32x4 acc[3][4];
#pragma unroll
    for (int i = 0; i < 3; i++)
#pragma unroll
        for (int j = 0; j < 4; j++) acc[i][j] = f32x4{0.f, 0.f, 0.f, 0.f};

    const unsigned short* Arow[3];
#pragma unroll
    for (int ri = 0; ri < 3; ri++)
        Arow[ri] = Ab + (size_t)(j0 + wj * 48 + ri * 16 + lr) * 1024 + lg * 8;

    bf16x8 Ac[2][3], An[2][3];

    // ---- prologue: stage tiles 0,1 ; load A(0). Queue: [s0:4][s1:4][A0:6]
#pragma unroll
    for (int i = 0; i < 4; i++) {
        int c = wave * 4 + i;
        gload_lds16(Bb + (size_t)(n0 + 8 * c + srow) * 1024 + 0 + sg16 * 8,
                    &Blds[0][c * 512]);
    }
#pragma unroll
    for (int i = 0; i < 4; i++) {
        int c = wave * 4 + i;
        gload_lds16(Bb + (size_t)(n0 + 8 * c + srow) * 1024 + 64 + sg16 * 8,
                    &Blds[1][c * 512]);
    }
#pragma unroll
    for (int h = 0; h < 2; h++)
#pragma unroll
        for (int ri = 0; ri < 3; ri++)
            Ac[h][ri] = __builtin_bit_cast(bf16x8,
                *reinterpret_cast<const short8*>(Arow[ri] + h * 32));
    __builtin_amdgcn_sched_barrier(0);
    asm volatile("s_waitcnt vmcnt(10)" ::: "memory");   // tile-0 staging landed
    __builtin_amdgcn_s_barrier();
    __builtin_amdgcn_sched_barrier(0);

#pragma unroll
    for (int t = 0; t < 16; ++t) {
        // ---- B fragments from swizzled LDS buf t%3
        const unsigned short* ldsB = &Blds[t % 3][0];
        bf16x8 Bfr[2][4];
#pragma unroll
        for (int h = 0; h < 2; h++)
#pragma unroll
            for (int ci = 0; ci < 4; ci++) {
                int row = wn * 64 + ci * 16 + lr;
                int sw  = (h * 4 + lg) ^ (lr & 7);
                Bfr[h][ci] = __builtin_bit_cast(bf16x8,
                    *reinterpret_cast<const short8*>(ldsB + row * 64 + sw * 8));
            }
        // ---- issue stage for tile t+2 (lands ~2 K-steps later)
        if (t < 14) {
#pragma unroll
            for (int i = 0; i < 4; i++) {
                int c = wave * 4 + i;
                gload_lds16(Bb + (size_t)(n0 + 8 * c + srow) * 1024 + (t + 2) * 64 + sg16 * 8,
                            &Blds[(t + 2) % 3][c * 512]);
            }
        }
        // ---- prefetch A for tile t+1
        if (t < 15) {
#pragma unroll
            for (int h = 0; h < 2; h++)
#pragma unroll
                for (int ri = 0; ri < 3; ri++)
                    An[h][ri] = __builtin_bit_cast(bf16x8,
                        *reinterpret_cast<const short8*>(Arow[ri] + (t + 1) * 64 + h * 32));
        }
        // ---- 24 MFMA (compiler waits lgkm for Bfr, vmcnt for Ac -> in-order
        //      drain also retires stage(t+1) before the next barrier)
#pragma unroll
        for (int h = 0; h < 2; h++)
#pragma unroll
            for (int ri = 0; ri < 3; ri++)
#pragma unroll
                for (int ci = 0; ci < 4; ci++)
                    acc[ri][ci] = __builtin_amdgcn_mfma_f32_16x16x32_bf16(
                        Ac[h][ri], Bfr[h][ci], acc[ri][ci], 0, 0, 0);
#pragma unroll
        for (int h = 0; h < 2; h++)
#pragma unroll
            for (int ri = 0; ri < 3; ri++)
                Ac[h][ri] = An[h][ri];     // SSA-folds under full unroll
        // steady state in flight: stage(t+2):4 + A(t+1):6 = 10
        asm volatile("s_waitcnt vmcnt(10)" ::: "memory");
        __builtin_amdgcn_s_barrier();
        __builtin_amdgcn_sched_barrier(0);
    }

    // ---- epilogue: D layout col = lane&15, row = (lane>>4)*4 + reg
    unsigned short* Cb = Cout + (size_t)b * 192 * 1024;
    const int jw = j0 + wj * 48;
    const int nw = n0 + wn * 64;
#pragma unroll
    for (int ri = 0; ri < 3; ri++)
#pragma unroll
        for (int ci = 0; ci < 4; ci++) {
            int col = nw + ci * 16 + lr;
#pragma unroll
            for (int r = 0; r < 4; r++) {
                int row = jw + ri * 16 + lg * 4 + r;
                Cb[(size_t)row * 1024 + col] = f32_to_bf16(acc[ri][ci][r]);
            }
        }
}

// ---------------------------------------------------------------------------
// final_contract: out[b,n,o,t] = relu( sum_f Th0[f,o]*xT + Th1[f,o]*r1 + Th2[f,o]*r2 )
// block = 192 threads (64 n x 3 tq), out tile staged in padded LDS,
// coalesced float4 copy-out. grid (16 n-chunks, 16 b).
// ---------------------------------------------------------------------------
#define OBUF_STRIDE 196   // 192 + 4 pad: 784B rows = 49x16B (aligned b128)

__global__ __launch_bounds__(192)
void final_contract(const unsigned short* __restrict__ xT,
                    const unsigned short* __restrict__ r1,
                    const unsigned short* __restrict__ r2,
                    const float* __restrict__ Theta,   // [3][16][16]
                    float* __restrict__ out)           // [B][1024][16][12]
{
    __shared__ float th[768];
    __shared__ float obuf[64 * OBUF_STRIDE];

    const int tid = threadIdx.x;
    for (int i = tid; i < 768; i += 192) th[i] = Theta[i];
    __syncthreads();

    const int b  = blockIdx.y;
    const int n0 = blockIdx.x * 64;
    const int nl = tid & 63;          // consecutive lanes = consecutive n
    const int tq = tid >> 6;          // 0..2

    float acc[4][16];
#pragma unroll
    for (int tt = 0; tt < 4; tt++)
#pragma unroll
        for (int o = 0; o < 16; o++) acc[tt][o] = 0.f;

    const size_t basep = (size_t)b * 192 * 1024 + n0 + nl;
#pragma unroll
    for (int f = 0; f < 16; f++) {
        size_t off = basep + (size_t)(f * 12 + tq * 4) * 1024;
        float v0[4], v1[4], v2[4];
#pragma unroll
        for (int tt = 0; tt < 4; tt++) {
            v0[tt] = bf16_to_f32(xT[off + (size_t)tt * 1024]);
            v1[tt] = bf16_to_f32(r1[off + (size_t)tt * 1024]);
            v2[tt] = bf16_to_f32(r2[off + (size_t)tt * 1024]);
        }
        const f32x4* t0 = reinterpret_cast<const f32x4*>(&th[0 * 256 + f * 16]);
        const f32x4* t1 = reinterpret_cast<const f32x4*>(&th[1 * 256 + f * 16]);
        const f32x4* t2 = reinterpret_cast<const f32x4*>(&th[2 * 256 + f * 16]);
#pragma unroll
        for (int q = 0; q < 4; q++) {
            f32x4 w0 = t0[q], w1 = t1[q], w2 = t2[q];
#pragma unroll
            for (int tt = 0; tt < 4; tt++)
#pragma unroll
                for (int e = 0; e < 4; e++)
                    acc[tt][q * 4 + e] += v0[tt] * w0[e] + v1[tt] * w1[e] + v2[tt] * w2[e];
        }
    }
    // store t-quads as float4 into padded LDS tile
#pragma unroll
    for (int o = 0; o < 16; o++) {
        f32x4 v;
#pragma unroll
        for (int tt = 0; tt < 4; tt++) v[tt] = fmaxf(acc[tt][o], 0.f);
        *reinterpret_cast<f32x4*>(&obuf[nl * OBUF_STRIDE + o * 12 + tq * 4]) = v;
    }
    __syncthreads();

    // coalesced copy-out: 64 rows x 192 f32 = 3072 float4, 16 per thread
    float* outp = out + ((size_t)b * 1024 + n0) * 192;
#pragma unroll
    for (int i = 0; i < 16; i++) {
        int v   = tid + i * 192;
        int row = v / 48;
        int c   = v - row * 48;
        *reinterpret_cast<f32x4*>(&outp[(size_t)v * 4]) =
            *reinterpret_cast<const f32x4*>(&obuf[row * OBUF_STRIDE + c * 4]);
    }
}

// ---------------------------------------------------------------------------
extern "C" void kernel_launch(void* const* d_in, const int* in_sizes, int n_in,
                              void* d_out, int out_size, void* d_ws, size_t ws_size,
                              hipStream_t stream)
{
    const float* x     = (const float*)d_in[0];   // [16][1024][16][12]
    const float* sa    = (const float*)d_in[1];   // [16][1024][1024]
    const float* adj   = (const float*)d_in[2];   // [1024][1024]
    const float* Theta = (const float*)d_in[3];   // [3][16][16]
    float* out = (float*)d_out;

    char* ws = (char*)d_ws;
    const size_t SZ_AT = (size_t)16 * 1024 * 1024 * 2;  // 32 MB
    const size_t SZ_XT = (size_t)16 * 192  * 1024 * 2;  //  6 MB
    unsigned short* aT = (unsigned short*)ws;
    unsigned short* xT = (unsigned short*)(ws + SZ_AT);
    unsigned short* r1 = (unsigned short*)(ws + SZ_AT + SZ_XT);
    unsigned short* r2 = (unsigned short*)(ws + SZ_AT + 2 * SZ_XT);

    prep_a<<<dim3(32, 32, 16), 256, 0, stream>>>(sa, adj, aT);
    prep_x<<<dim3(32, 6, 16), 256, 0, stream>>>(x, xT);
    gemm_tn<<<dim3(8, 2, 16), 256, 0, stream>>>(xT, aT, r1);   // rhs1T
    gemm_tn<<<dim3(8, 2, 16), 256, 0, stream>>>(r1, aT, r2);   // rhs2T
    final_contract<<<dim3(16, 16), 192, 0, stream>>>(xT, r1, r2, Theta, out);
}